// Round 2
// baseline (181.627 us; speedup 1.0000x reference)
//
#include <hip/hip_runtime.h>
#include <hip/hip_fp16.h>

constexpr int S_LEN  = 2048;
constexpr int HID    = 1024;
constexpr int HEADS  = 16;
constexpr int HDIM   = 64;
constexpr int BATCH  = 2;
constexpr int BH     = BATCH * HEADS;          // 32
constexpr int M_ROWS = BATCH * S_LEN;          // 4096

typedef _Float16 half8  __attribute__((ext_vector_type(8)));
typedef _Float16 half4v __attribute__((ext_vector_type(4)));
typedef _Float16 half2v __attribute__((ext_vector_type(2)));
typedef float    f32x4  __attribute__((ext_vector_type(4)));
typedef float    f32x16 __attribute__((ext_vector_type(16)));
typedef unsigned uint4v __attribute__((ext_vector_type(4)));

constexpr float EXP2_OFF = -11.541560327111707f;   // -8*log2(e)
constexpr float Q_SCALE  = 0.18033688011112042f;   // 0.125*log2(e)

// ---------------------------------------------------------------------------
// Kernel 0: fp32 -> fp16 convert for X, Wq, Wk, Wv; mask -> fp32 exp2-bias.
// ---------------------------------------------------------------------------
__global__ __launch_bounds__(256) void cvt_kernel(
    const float* __restrict__ X,  const float* __restrict__ Wq,
    const float* __restrict__ Wk, const float* __restrict__ Wv,
    const int* __restrict__ mask,
    _Float16* __restrict__ Xh,  _Float16* __restrict__ Wqh,
    _Float16* __restrict__ Wkh, _Float16* __restrict__ Wvh,
    float* __restrict__ maskF)
{
    const int blk = blockIdx.x;
    if (blk >= 3584) {                       // mask: 2 blocks x 2048 elements
        const int loc = blk - 3584;
        const size_t e = ((size_t)loc * 256 + threadIdx.x) * 8;
        #pragma unroll
        for (int i = 0; i < 8; ++i)
            maskF[e + i] = mask[e + i] ? EXP2_OFF : -1.0e30f;
        return;
    }
    const float* src; _Float16* dst; int loc;
    if (blk < 2048)      { src = X;  dst = Xh;  loc = blk; }
    else if (blk < 2560) { src = Wq; dst = Wqh; loc = blk - 2048; }
    else if (blk < 3072) { src = Wk; dst = Wkh; loc = blk - 2560; }
    else                 { src = Wv; dst = Wvh; loc = blk - 3072; }
    const size_t e = ((size_t)loc * 256 + threadIdx.x) * 8;
    float4 a = *reinterpret_cast<const float4*>(&src[e]);
    float4 b = *reinterpret_cast<const float4*>(&src[e + 4]);
    half8 h = { (_Float16)a.x, (_Float16)a.y, (_Float16)a.z, (_Float16)a.w,
                (_Float16)b.x, (_Float16)b.y, (_Float16)b.z, (_Float16)b.w };
    *reinterpret_cast<half8*>(&dst[e]) = h;
}

// ---------------------------------------------------------------------------
__device__ __forceinline__ void async_cp16(_Float16* lds, const _Float16* g) {
    __builtin_amdgcn_global_load_lds(
        (const __attribute__((address_space(1))) void*)g,
        (__attribute__((address_space(3))) void*)lds, 16, 0, 0);
}

// v_permlane32_swap_b32: swaps lanes[32:63] of x with lanes[0:31] of y.
// After: x = (x.row0, y.row0), y = (x.row1, y.row1).
__device__ __forceinline__ void permlane32_swap(unsigned &x, unsigned &y) {
    asm("v_permlane32_swap_b32 %0, %1" : "+v"(x), "+v"(y));
}

// ---------------------------------------------------------------------------
// Kernel A: QKV projection (unchanged this round).
// ---------------------------------------------------------------------------
__global__ __launch_bounds__(256) void qkv_proj_kernel(
    const _Float16* __restrict__ Xh,
    const _Float16* __restrict__ Wqh, const _Float16* __restrict__ Wkh,
    const _Float16* __restrict__ Wvh,
    const float* __restrict__ bq, const float* __restrict__ bk,
    const float* __restrict__ bv,
    _Float16* __restrict__ Qo, _Float16* __restrict__ Ko,
    _Float16* __restrict__ Vt)
{
    const int mode = blockIdx.z;
    const _Float16* W    = (mode == 0) ? Wqh : (mode == 1) ? Wkh : Wvh;
    const float*    bias = (mode == 0) ? bq  : (mode == 1) ? bk  : bv;

    const int m0 = blockIdx.x * 128, n0 = blockIdx.y * 128;
    const int tid = threadIdx.x, wave = tid >> 6, lane = tid & 63;
    const int l31 = lane & 31, kg = lane >> 5;      // kg: k-half group (0/1)

    __shared__ _Float16 SMEM[18432];

    f32x16 acc[2][2];
    #pragma unroll
    for (int mt = 0; mt < 2; ++mt)
        #pragma unroll
        for (int nt = 0; nt < 2; ++nt)
            #pragma unroll
            for (int i = 0; i < 16; ++i) acc[mt][nt][i] = 0.f;

    const int wm = (wave & 1) * 64, wn = (wave >> 1) * 64;

    const int srow = tid >> 2, spos = tid & 3;
    auto stage = [&](int k0, int b) {
        _Float16* Asb = SMEM + b * 8192;
        _Float16* Bsb = Asb + 4096;
        #pragma unroll
        for (int j = 0; j < 2; ++j) {
            const int row = srow + j * 64;
            const int sch = spos ^ (row & 3);
            async_cp16(&Asb[j * 2048 + tid * 8],
                       &Xh[(size_t)(m0 + row) * HID + k0 + sch * 8]);
            async_cp16(&Bsb[j * 2048 + tid * 8],
                       &W [(size_t)(n0 + row) * HID + k0 + sch * 8]);
        }
    };

    stage(0, 0);
    int buf = 0;

    for (int k0 = 0; k0 < HID; k0 += 32) {
        __syncthreads();
        if (k0 + 32 < HID) stage(k0 + 32, buf ^ 1);
        _Float16* Asb = SMEM + buf * 8192;
        _Float16* Bsb = Asb + 4096;

        #pragma unroll
        for (int c = 0; c < 2; ++c) {               // two k-16 chunks
            const int k8 = c * 2 + kg;              // 16B chunk idx (0..3)
            half8 af[2], bf[2];
            #pragma unroll
            for (int mt = 0; mt < 2; ++mt) {
                const int row = wm + mt * 32 + l31;
                af[mt] = *reinterpret_cast<const half8*>(
                    &Asb[row * 32 + ((k8 ^ (row & 3)) * 8)]);
            }
            #pragma unroll
            for (int nt = 0; nt < 2; ++nt) {
                const int row = wn + nt * 32 + l31;
                bf[nt] = *reinterpret_cast<const half8*>(
                    &Bsb[row * 32 + ((k8 ^ (row & 3)) * 8)]);
            }
            #pragma unroll
            for (int mt = 0; mt < 2; ++mt)
                #pragma unroll
                for (int nt = 0; nt < 2; ++nt)
                    acc[mt][nt] = __builtin_amdgcn_mfma_f32_32x32x16_f16(
                        af[mt], bf[nt], acc[mt][nt], 0, 0, 0);
        }
        buf ^= 1;
    }
    __syncthreads();                       // staging LDS dead -> reuse for T

    _Float16* T = SMEM + wave * 4608;      // wave-private [64][72]

    const int nn  = n0 + wn;               // 64-aligned -> single head
    const int hh  = nn >> 6;
    const int mm  = m0 + wm;               // 64-aligned -> single batch
    const int bb  = mm >> 11;
    const int bhv = bb * HEADS + hh;
    const int s0  = mm & 2047;
    const int rowg = lane >> 3, chunk = lane & 7;   // store-phase mapping

    if (mode < 2) {
        _Float16* Out = (mode == 0) ? Qo : Ko;
        #pragma unroll
        for (int nt = 0; nt < 2; ++nt) {
            const int col = nt * 32 + l31;
            float bias_n = bias[nn + col];
            #pragma unroll
            for (int mt = 0; mt < 2; ++mt)
                #pragma unroll
                for (int r = 0; r < 16; ++r) {
                    const int row_l = (r & 3) + 8 * (r >> 2) + 4 * kg;
                    float v = acc[mt][nt][r] + bias_n;
                    if (mode == 0) v *= Q_SCALE;
                    T[(mt * 32 + row_l) * 72 + col] = (_Float16)v;
                }
        }
        asm volatile("s_waitcnt lgkmcnt(0)" ::: "memory");   // wave-private
        #pragma unroll
        for (int j = 0; j < 8; ++j) {
            const int sr = j * 8 + rowg;
            half8 v = *reinterpret_cast<const half8*>(&T[sr * 72 + chunk * 8]);
            *reinterpret_cast<half8*>(
                &Out[((size_t)bhv * S_LEN + s0 + sr) * HDIM + chunk * 8]) = v;
        }
    } else {
        #pragma unroll
        for (int nt = 0; nt < 2; ++nt) {
            const int col = nt * 32 + l31;
            const float bias_n = bias[nn + col];
            #pragma unroll
            for (int mt = 0; mt < 2; ++mt)
                #pragma unroll
                for (int rg = 0; rg < 4; ++rg) {
                    half4v t = { (_Float16)(acc[mt][nt][rg * 4 + 0] + bias_n),
                                 (_Float16)(acc[mt][nt][rg * 4 + 1] + bias_n),
                                 (_Float16)(acc[mt][nt][rg * 4 + 2] + bias_n),
                                 (_Float16)(acc[mt][nt][rg * 4 + 3] + bias_n) };
                    const int s_off = mt * 32 + 8 * rg + 4 * kg;
                    *reinterpret_cast<half4v*>(&T[col * 72 + s_off]) = t;
                }
        }
        asm volatile("s_waitcnt lgkmcnt(0)" ::: "memory");   // wave-private
        #pragma unroll
        for (int j = 0; j < 8; ++j) {
            const int dr = j * 8 + rowg;
            half8 v = *reinterpret_cast<const half8*>(&T[dr * 72 + chunk * 8]);
            *reinterpret_cast<half8*>(
                &Vt[((size_t)bhv * HDIM + dr) * S_LEN + s0 + chunk * 8]) = v;
        }
    }
}

// ---------------------------------------------------------------------------
// Kernel B: attention, 32x32 swapped-QK^T rebuild — P never touches LDS.
//   256 threads (4 waves x 32 q-rows = 128 q-rows/block), grid 512
//   (XCD-swizzled, 16 q-tiles x 32 bh).  K/V^T double-buffered in LDS
//   (32 KB total), XOR chunk-swizzle, one barrier/iter.
//   S^T = K.Q^T via mfma_f32_32x32x16_f16: lane holds P[key...][q=l31];
//   PV B-operand built in-register: cvt_pkrtz pairs + v_permlane32_swap_b32
//   (kg<->kg+32 half exchange).  No Ps buffer, no mid-iter lgkmcnt(0).
// ---------------------------------------------------------------------------
__global__ __launch_bounds__(256) void attn_kernel(
    const _Float16* __restrict__ Q, const _Float16* __restrict__ K,
    const _Float16* __restrict__ Vt, const float* __restrict__ maskF,
    float* __restrict__ Out)
{
    const int id    = blockIdx.x;
    const int xcd   = id & 7, local = id >> 3;      // local 0..63
    const int bh    = xcd * 4 + (local & 3);        // 4 bh per XCD
    const int qt    = local >> 2;                   // 0..15
    const int b = bh >> 4, h = bh & 15;
    const int tid = threadIdx.x, wave = tid >> 6, lane = tid & 63;
    const int l31 = lane & 31, kg = lane >> 5;

    __shared__ _Float16 Ks[2][64 * 64];             // 8KB x2, swizzled chunks
    __shared__ _Float16 Vs[2][64 * 64];             // 8KB x2, swizzled chunks

    const _Float16* Qb = Q  + (size_t)bh * S_LEN * HDIM;
    const _Float16* Kb = K  + (size_t)bh * S_LEN * HDIM;
    const _Float16* Vb = Vt + (size_t)bh * HDIM * S_LEN;
    const float*    mb = maskF + b * S_LEN;

    // one 32-q tile per wave; q = l31 column of the 32x32 MFMA
    const int qrow = qt * 128 + wave * 32 + l31;

    // Q fragments: B-operand, B[k = kc*16 + kg*8 + j][col=l31] = Q[qrow][d]
    half8 qf[4];
    #pragma unroll
    for (int kc = 0; kc < 4; ++kc)
        qf[kc] = *reinterpret_cast<const half8*>(
            &Qb[(size_t)qrow * HDIM + kc * 16 + kg * 8]);

    f32x16 acc[2];
    #pragma unroll
    for (int dt = 0; dt < 2; ++dt)
        #pragma unroll
        for (int i = 0; i < 16; ++i) acc[dt][i] = 0.f;
    float den = 0.f;

    // staging: 256 lanes x 2 x 16B per tile = full 64x64 fp16 tile.
    const int srow_t = tid >> 3;                          // 0..31
    const int sch    = (tid & 7) ^ (srow_t & 7);          // XOR swizzle
    auto stage = [&](int kb, int buf) {
        #pragma unroll
        for (int j = 0; j < 2; ++j) {
            const int row = srow_t + j * 32;
            async_cp16(&Ks[buf][j * 2048 + tid * 8],
                       &Kb[(size_t)(kb + row) * HDIM + sch * 8]);
            async_cp16(&Vs[buf][j * 2048 + tid * 8],
                       &Vb[(size_t)row * S_LEN + kb + sch * 8]);
        }
    };

    stage(0, 0);
    int buf = 0;
    const int rsw = l31 & 7;            // read-side swizzle key (row&7)

    for (int kb = 0; kb < S_LEN; kb += 64) {
        __syncthreads();                  // drains staging of `buf` + prev compute
        if (kb + 64 < S_LEN) stage(kb + 64, buf ^ 1);

        // ---- S^T = K.Q^T : 2 key-tiles x 4 k-chunks of 32x32x16 ----
        f32x16 sc[2];
        #pragma unroll
        for (int kt = 0; kt < 2; ++kt) {
            #pragma unroll
            for (int i = 0; i < 16; ++i) sc[kt][i] = 0.f;
            half8 kf[4];
            #pragma unroll
            for (int kc = 0; kc < 4; ++kc)
                kf[kc] = *reinterpret_cast<const half8*>(
                    &Ks[buf][(kt * 32 + l31) * 64 + (((kc * 2 + kg) ^ rsw) * 8)]);
            #pragma unroll
            for (int kc = 0; kc < 4; ++kc)
                sc[kt] = __builtin_amdgcn_mfma_f32_32x32x16_f16(
                    kf[kc], qf[kc], sc[kt], 0, 0, 0);
        }

        // ---- V fragments (A-operand for PV) ----
        half8 vf[2][4];
        #pragma unroll
        for (int dt = 0; dt < 2; ++dt)
            #pragma unroll
            for (int kc = 0; kc < 4; ++kc)
                vf[dt][kc] = *reinterpret_cast<const half8*>(
                    &Vs[buf][(dt * 32 + l31) * 64 + (((kc * 2 + kg) ^ rsw) * 8)]);

        // ---- per key-tile: p = 2^(s+bias); build P^T frags in-register ----
        #pragma unroll
        for (int kt = 0; kt < 2; ++kt) {
            float4 mm[4];
            #pragma unroll
            for (int g = 0; g < 4; ++g)
                mm[g] = *reinterpret_cast<const float4*>(
                    &mb[kb + kt * 32 + g * 8 + kg * 4]);

            float p[16];
            #pragma unroll
            for (int r = 0; r < 16; ++r) {
                const float* m4 = reinterpret_cast<const float*>(&mm[r >> 2]);
                p[r] = __builtin_amdgcn_exp2f(sc[kt][r] + m4[r & 3]);
            }
            den += (((p[0] + p[1]) + (p[2] + p[3])) +
                    ((p[4] + p[5]) + (p[6] + p[7]))) +
                   (((p[8] + p[9]) + (p[10] + p[11])) +
                    ((p[12] + p[13]) + (p[14] + p[15])));

            #pragma unroll
            for (int hh = 0; hh < 2; ++hh) {
                // keys of PV chunk kc2: kt*32 + hh*16 + kg*8 + j
                unsigned a0 = __builtin_bit_cast(unsigned,
                    __builtin_amdgcn_cvt_pkrtz(p[hh * 8 + 0], p[hh * 8 + 1]));
                unsigned a1 = __builtin_bit_cast(unsigned,
                    __builtin_amdgcn_cvt_pkrtz(p[hh * 8 + 2], p[hh * 8 + 3]));
                unsigned b0 = __builtin_bit_cast(unsigned,
                    __builtin_amdgcn_cvt_pkrtz(p[hh * 8 + 4], p[hh * 8 + 5]));
                unsigned b1 = __builtin_bit_cast(unsigned,
                    __builtin_amdgcn_cvt_pkrtz(p[hh * 8 + 6], p[hh * 8 + 7]));
                permlane32_swap(a0, b0);   // a0 = d0, b0 = d2
                permlane32_swap(a1, b1);   // a1 = d1, b1 = d3
                uint4v pd = { a0, a1, b0, b1 };
                half8 pf = __builtin_bit_cast(half8, pd);
                const int kc2 = kt * 2 + hh;
                acc[0] = __builtin_amdgcn_mfma_f32_32x32x16_f16(
                    vf[0][kc2], pf, acc[0], 0, 0, 0);
                acc[1] = __builtin_amdgcn_mfma_f32_32x32x16_f16(
                    vf[1][kc2], pf, acc[1], 0, 0, 0);
            }
        }
        buf ^= 1;
    }

    // ---- denominator: q = l31; combine kg halves ----
    den += __shfl_xor(den, 32, 64);
    const float inv = 1.0f / den;

    // ---- epilogue: O^T[d][q]: d = dt*32 + 8*(r>>2) + 4*kg + (r&3) ----
    float* orow = Out + ((size_t)(b * S_LEN + qrow)) * HID + h * HDIM;
    #pragma unroll
    for (int dt = 0; dt < 2; ++dt)
        #pragma unroll
        for (int g = 0; g < 4; ++g) {
            float4 o = { acc[dt][g * 4 + 0] * inv, acc[dt][g * 4 + 1] * inv,
                         acc[dt][g * 4 + 2] * inv, acc[dt][g * 4 + 3] * inv };
            *reinterpret_cast<float4*>(&orow[dt * 32 + g * 8 + kg * 4]) = o;
        }
}

// ---------------------------------------------------------------------------
extern "C" void kernel_launch(void* const* d_in, const int* in_sizes, int n_in,
                              void* d_out, int out_size, void* d_ws, size_t ws_size,
                              hipStream_t stream) {
    const float* X  = (const float*)d_in[0];
    const int*   mk = (const int*)  d_in[1];
    const float* Wq = (const float*)d_in[2];
    const float* bq = (const float*)d_in[3];
    const float* Wk = (const float*)d_in[4];
    const float* bk = (const float*)d_in[5];
    const float* Wv = (const float*)d_in[6];
    const float* bv = (const float*)d_in[7];
    float* out = (float*)d_out;

    // ws (halves): [Xh 4M][Wqh 1M][Wkh 1M][Wvh 1M][Q 4M][K 4M][Vt 4M][maskF]
    _Float16* Xh  = (_Float16*)d_ws;
    _Float16* Wqh = Xh  + (size_t)M_ROWS * HID;
    _Float16* Wkh = Wqh + (size_t)HID * HID;
    _Float16* Wvh = Wkh + (size_t)HID * HID;
    _Float16* Q   = Wvh + (size_t)HID * HID;
    _Float16* K   = Q   + (size_t)BH * S_LEN * HDIM;
    _Float16* Vt  = K   + (size_t)BH * S_LEN * HDIM;
    float*    maskF = (float*)(Vt + (size_t)BH * S_LEN * HDIM);

    cvt_kernel<<<3586, 256, 0, stream>>>(X, Wq, Wk, Wv, mk, Xh, Wqh, Wkh, Wvh, maskF);

    dim3 gp(M_ROWS / 128, HID / 128, 3);
    qkv_proj_kernel<<<gp, 256, 0, stream>>>(Xh, Wqh, Wkh, Wvh, bq, bk, bv, Q, K, Vt);

    attn_kernel<<<512, 256, 0, stream>>>(Q, K, Vt, maskF, out);
}